// Round 3
// baseline (267.739 us; speedup 1.0000x reference)
//
#include <hip/hip_runtime.h>
#include <math.h>

#define LSEQ 4096
#define MFFT 8192
#define NM   64
#define NBH  4096
#define TMAIN 512

__device__ __forceinline__ float2 cmulf(float2 a, float2 b) {
  return make_float2(a.x*b.x - a.y*b.y, a.x*b.y + a.y*b.x);
}
__device__ __forceinline__ float2 caddf(float2 a, float2 b){ return make_float2(a.x+b.x, a.y+b.y); }
__device__ __forceinline__ float2 csubf(float2 a, float2 b){ return make_float2(a.x-b.x, a.y-b.y); }
__device__ __forceinline__ float2 conjf(float2 a){ return make_float2(a.x, -a.y); }

// ---- radix-4 butterflies (identical math to the validated r1 kernel) ----
__device__ __forceinline__ void r4_fwd(float2& x0, float2& x1, float2& x2, float2& x3,
                                       float2 w1, float2 w2, float2 w3) {
  float2 A = caddf(x0,x2), C = csubf(x0,x2);
  float2 B = caddf(x1,x3), D = csubf(x1,x3);
  float2 y1 = make_float2(C.x + D.y, C.y - D.x);   // C - iD
  float2 y3 = make_float2(C.x - D.y, C.y + D.x);   // C + iD
  x0 = caddf(A,B);
  x1 = cmulf(y1,w1);
  x2 = cmulf(csubf(A,B),w2);
  x3 = cmulf(y3,w3);
}
__device__ __forceinline__ void r4_inv(float2& y0, float2& y1, float2& y2, float2& y3,
                                       float2 w1c, float2 w2c, float2 w3c) {
  float2 c1 = cmulf(y1,w1c);
  float2 c2 = cmulf(y2,w2c);
  float2 c3 = cmulf(y3,w3c);
  float2 ap = caddf(y0,c2), bp = csubf(y0,c2);
  float2 cp = caddf(c1,c3);
  float2 dp = make_float2(c3.y - c1.y, c1.x - c3.x);  // i*(c1-c3)
  y0 = caddf(ap,cp); y1 = caddf(bp,dp); y2 = csubf(ap,cp); y3 = csubf(bp,dp);
}

// compile-time twiddle constants: c16[k]=W16^k, c8[k]=W16^2k, c163[k]=W16^3k (W=e^-2pi i/16)
#define C16R0 1.f
#define DECL_CONSTS \
  const float C16R[4]={1.f,0.9238795325112867f,0.7071067811865476f,0.3826834323650898f}; \
  const float C16I[4]={0.f,-0.3826834323650898f,-0.7071067811865476f,-0.9238795325112867f}; \
  const float C8R[4] ={1.f,0.7071067811865476f,0.f,-0.7071067811865476f}; \
  const float C8I[4] ={0.f,-0.7071067811865476f,-1.f,-0.7071067811865476f}; \
  const float C163R[4]={1.f,0.3826834323650898f,-0.7071067811865476f,-0.9238795325112867f}; \
  const float C163I[4]={0.f,-0.9238795325112867f,-0.7071067811865476f,0.3826834323650898f};

// fused radix-16 forward = radix-4 at stride 4t then radix-4 at stride t (in regs)
__device__ __forceinline__ void r16_fwd(float2 x[16], float2 wA) {
  DECL_CONSTS
  float2 wA2 = cmulf(wA,wA), wA3 = cmulf(wA2,wA);
  #pragma unroll
  for (int k0 = 0; k0 < 4; k0++) {
    float2 w1 = cmulf(wA,  make_float2(C16R[k0],C16I[k0]));
    float2 w2 = cmulf(wA2, make_float2(C8R[k0], C8I[k0]));
    float2 w3 = cmulf(wA3, make_float2(C163R[k0],C163I[k0]));
    r4_fwd(x[k0], x[k0+4], x[k0+8], x[k0+12], w1, w2, w3);
  }
  float2 wB = cmulf(wA2,wA2);
  float2 wB2 = cmulf(wB,wB), wB3 = cmulf(wB2,wB);
  #pragma unroll
  for (int q = 0; q < 4; q++)
    r4_fwd(x[4*q], x[4*q+1], x[4*q+2], x[4*q+3], wB, wB2, wB3);
}
// fused radix-16 inverse: levels reversed, twiddles conjugated
__device__ __forceinline__ void r16_inv(float2 x[16], float2 wA) {
  DECL_CONSTS
  float2 wA2 = cmulf(wA,wA), wA3 = cmulf(wA2,wA);
  float2 wB = cmulf(wA2,wA2);
  float2 wB2 = cmulf(wB,wB), wB3 = cmulf(wB2,wB);
  float2 wBc = conjf(wB), wB2c = conjf(wB2), wB3c = conjf(wB3);
  #pragma unroll
  for (int q = 0; q < 4; q++)
    r4_inv(x[4*q], x[4*q+1], x[4*q+2], x[4*q+3], wBc, wB2c, wB3c);
  #pragma unroll
  for (int k0 = 0; k0 < 4; k0++) {
    float2 w1c = conjf(cmulf(wA,  make_float2(C16R[k0],C16I[k0])));
    float2 w2c = conjf(cmulf(wA2, make_float2(C8R[k0], C8I[k0])));
    float2 w3c = conjf(cmulf(wA3, make_float2(C163R[k0],C163I[k0])));
    r4_inv(x[k0], x[k0+4], x[k0+8], x[k0+12], w1c, w2c, w3c);
  }
}

// ---------------- prep: twiddle tables ----------------
// ctg[0..511]   = W^t        (P1/P5, t = tid)
// ctg[512..543] = W^{16 j}   (P2/P4, j = tid&31)
// ctg[544..559] = W^{256 c}  (r2 stage, c = tid&15)       W = e^{-2pi i/8192}
__global__ void tables_kernel(float2* __restrict__ ctg) {
  int t = blockIdx.x*blockDim.x + threadIdx.x;
  if (t >= 560) return;
  int e = (t < 512) ? t : (t < 544) ? 16*(t-512) : 256*(t-544);
  double ang = -2.0*M_PI*(double)e/(double)MFFT;
  ctg[t] = make_float2((float)cos(ang), (float)sin(ang));
}

// ---------------- prep: at_roots[k] via 4 Cauchy dots (double precision) ----------------
__global__ void cauchy_kernel(const float* __restrict__ Lre, const float* __restrict__ Lim,
                              const float* __restrict__ Pre, const float* __restrict__ Pim,
                              const float* __restrict__ Bre, const float* __restrict__ Bim,
                              const float* __restrict__ Cri, const float* __restrict__ lstep,
                              float2* __restrict__ a_out) {
  int k = blockIdx.x*blockDim.x + threadIdx.x;
  if (k >= LSEQ) return;
  double step = exp((double)lstep[0]);
  double ang = -2.0*M_PI*(double)k/(double)LSEQ;
  double wr = cos(ang), wi = sin(ang);
  double nr = 1.0 - wr, ni = -wi;
  double dr = 1.0 + wr, di = wi;
  double dn = dr*dr + di*di;
  double gre = (2.0/step) * (nr*dr + ni*di)/dn;
  double gim = (2.0/step) * (ni*dr - nr*di)/dn;
  double cre = 2.0*dr/dn, cim = -2.0*di/dn;
  double k00r=0,k00i=0,k01r=0,k01i=0,k10r=0,k10i=0,k11r=0,k11i=0;
  for (int n = 0; n < NM; n++) {
    double lre = Lre[n], lim = Lim[n];
    double pre = Pre[n], pim = Pim[n];
    double bre = Bre[n], bim = Bim[n];
    double ccr = Cri[2*n], cci = Cri[2*n+1];
    double er = gre - lre, ei = gim - lim;
    double inv = 1.0/(er*er + ei*ei);
    double ir =  er*inv, ii = -ei*inv;
    double v00r = ccr*bre + cci*bim, v00i = ccr*bim - cci*bre;
    double v01r = ccr*pre + cci*pim, v01i = ccr*pim - cci*pre;
    double v10r = pre*bre + pim*bim, v10i = pre*bim - pim*bre;
    double v11r = pre*pre + pim*pim, v11i = 0.0;
    k00r += v00r*ir - v00i*ii;  k00i += v00r*ii + v00i*ir;
    k01r += v01r*ir - v01i*ii;  k01i += v01r*ii + v01i*ir;
    k10r += v10r*ir - v10i*ii;  k10i += v10r*ii + v10i*ir;
    k11r += v11r*ir - v11i*ii;  k11i += v11r*ii + v11i*ir;
  }
  double numr = k01r*k10r - k01i*k10i, numi = k01r*k10i + k01i*k10r;
  double der = 1.0 + k11r, dei = k11i;
  double dinv = 1.0/(der*der + dei*dei);
  double qr = (numr*der + numi*dei)*dinv;
  double qi = (numi*der - numr*dei)*dinv;
  double tr = k00r - qr, ti = k00i - qi;
  double ar = cre*tr - cim*ti, ai = cre*ti + cim*tr;
  a_out[k] = make_float2((float)ar, (float)ai);
}

// ---------------- prep: K[l] = Re(IDFT_L(a))[l], 64 lanes per output ----------------
__global__ void ktime_kernel(const float2* __restrict__ a, float* __restrict__ K) {
  int lane = threadIdx.x & 63;
  int l = blockIdx.x * (blockDim.x >> 6) + (threadIdx.x >> 6);
  if (l >= LSEQ) return;
  double ang0 = 2.0*M_PI*(double)((l*lane) & (LSEQ-1))/(double)LSEQ;
  double tr = cos(ang0), ti = sin(ang0);
  double ang1 = 2.0*M_PI*(double)(l & 63)/64.0;
  double wr = cos(ang1), wi = sin(ang1);
  double acc = 0.0;
  for (int k = 0; k < 64; k++) {
    float2 ak = a[lane + (k << 6)];
    acc += (double)ak.x*tr - (double)ak.y*ti;
    double ntr = tr*wr - ti*wi;
    ti = tr*wi + ti*wr;
    tr = ntr;
  }
  for (int off = 32; off > 0; off >>= 1) acc += __shfl_down(acc, off);
  if (lane == 0) K[l] = (float)(acc/(double)LSEQ);
}

// ---------------- prep: Kd = fwd chain(pad(K)) / M, stored at logical slot 16*tid+c ----
__global__ void kd_kernel(const float* __restrict__ K, const float2* __restrict__ ctg,
                          float2* __restrict__ Kd) {
  __shared__ float2 z[MFFT];
  const int tid = threadIdx.x;
  float2 x[16];
  // P1: t=512
  #pragma unroll
  for (int k = 0; k < 8; k++) x[k] = make_float2(K[tid + 512*k], 0.f);
  #pragma unroll
  for (int k = 8; k < 16; k++) x[k] = make_float2(0.f, 0.f);
  r16_fwd(x, ctg[tid]);
  {
    int xc = (tid >> 5) & 15; int p0 = tid ^ xc;
    #pragma unroll
    for (int k = 0; k < 16; k++) z[p0 + 512*k] = x[k];
  }
  __syncthreads();
  // P2: t=32 + r2(s=16) tail via shfl
  const int j5 = tid & 31;
  const int Gb = (tid >> 5) << 9;
  #pragma unroll
  for (int k = 0; k < 16; k++) x[k] = z[Gb + 32*k + (j5 ^ k)];
  r16_fwd(x, ctg[512 + j5]);
  {
    bool hi = (tid >> 4) & 1;
    float2 w32 = ctg[544 + (tid & 15)];
    float2 weff = hi ? w32 : make_float2(1.f, 0.f);
    float s = hi ? -1.f : 1.f;
    #pragma unroll
    for (int k = 0; k < 16; k++) {
      float rx = __shfl_xor(x[k].x, 16);
      float ry = __shfl_xor(x[k].y, 16);
      float2 pre = make_float2(fmaf(x[k].x, s, rx), fmaf(x[k].y, s, ry));
      x[k] = cmulf(pre, weff);
    }
  }
  #pragma unroll
  for (int k = 0; k < 16; k++) z[Gb + 32*k + (j5 ^ k)] = x[k];
  __syncthreads();
  // P3: consecutive, constant-twiddle r16, scale, store
  {
    int xc = (tid >> 1) & 15; int b16 = tid << 4;
    #pragma unroll
    for (int c = 0; c < 16; c++) x[c] = z[b16 + (c ^ xc)];
    r16_fwd(x, make_float2(1.f, 0.f));
    const float sc = 1.0f/(float)MFFT;
    #pragma unroll
    for (int c = 0; c < 16; c++)
      Kd[b16 + c] = make_float2(x[c].x*sc, x[c].y*sc);
  }
}

// ---------------- main: 2 rows per block, 5 passes, 4 barriers ----------------
__global__ __launch_bounds__(TMAIN, 4)
void conv_kernel(const float* __restrict__ u, const float* __restrict__ Dp,
                 const float2* __restrict__ ctg, const float2* __restrict__ Kd,
                 float* __restrict__ out) {
  __shared__ float2 z[MFFT];
  const int tid = threadIdx.x;
  const int r0 = blockIdx.x, r1 = blockIdx.x + (NBH/2);
  const float* u0 = u + (size_t)r0*LSEQ;
  const float* u1 = u + (size_t)r1*LSEQ;
  float2 x[16];
  // ---- P1: global->regs, r16 fwd (t=512), regs->LDS ----
  #pragma unroll
  for (int k = 0; k < 8; k++)
    x[k] = make_float2(u0[tid + 512*k], u1[tid + 512*k]);
  #pragma unroll
  for (int k = 8; k < 16; k++) x[k] = make_float2(0.f, 0.f);
  const float2 wA1 = ctg[tid];
  r16_fwd(x, wA1);
  {
    int xc = (tid >> 5) & 15; int p0 = tid ^ xc;
    #pragma unroll
    for (int k = 0; k < 16; k++) z[p0 + 512*k] = x[k];
  }
  __syncthreads();
  // ---- P2: r16 fwd (t=32) + r2(s=16) tail via shfl_xor(16) ----
  const int j5 = tid & 31;
  const int Gb = (tid >> 5) << 9;
  #pragma unroll
  for (int k = 0; k < 16; k++) x[k] = z[Gb + 32*k + (j5 ^ k)];
  const float2 wA2t = ctg[512 + j5];
  r16_fwd(x, wA2t);
  {
    bool hi = (tid >> 4) & 1;
    float2 w32 = ctg[544 + (tid & 15)];
    float2 weff = hi ? w32 : make_float2(1.f, 0.f);
    float s = hi ? -1.f : 1.f;
    #pragma unroll
    for (int k = 0; k < 16; k++) {
      float rx = __shfl_xor(x[k].x, 16);
      float ry = __shfl_xor(x[k].y, 16);
      float2 pre = make_float2(fmaf(x[k].x, s, rx), fmaf(x[k].y, s, ry));
      x[k] = cmulf(pre, weff);
    }
  }
  #pragma unroll
  for (int k = 0; k < 16; k++) z[Gb + 32*k + (j5 ^ k)] = x[k];
  __syncthreads();
  // ---- P3: consecutive; const-twiddle r16 fwd; x Kd; const-twiddle r16 inv ----
  {
    int xc = (tid >> 1) & 15; int b16 = tid << 4;
    #pragma unroll
    for (int c = 0; c < 16; c++) x[c] = z[b16 + (c ^ xc)];
    float4 kd[8];
    const float4* Kd4 = (const float4*)(Kd + b16);
    #pragma unroll
    for (int q = 0; q < 8; q++) kd[q] = Kd4[q];
    r16_fwd(x, make_float2(1.f, 0.f));
    #pragma unroll
    for (int c = 0; c < 8; c++) {
      x[2*c]   = cmulf(x[2*c],   make_float2(kd[c].x, kd[c].y));
      x[2*c+1] = cmulf(x[2*c+1], make_float2(kd[c].z, kd[c].w));
    }
    r16_inv(x, make_float2(1.f, 0.f));
    #pragma unroll
    for (int c = 0; c < 16; c++) z[b16 + (c ^ xc)] = x[c];
  }
  __syncthreads();
  // ---- P4: inv r2(s=16) head via shfl + r16 inv (t=32) ----
  {
    #pragma unroll
    for (int k = 0; k < 16; k++) x[k] = z[Gb + 32*k + (j5 ^ k)];
    bool hi = (tid >> 4) & 1;
    float2 w32 = ctg[544 + (tid & 15)];
    float2 weffc = hi ? conjf(w32) : make_float2(1.f, 0.f);
    float s = hi ? -1.f : 1.f;
    #pragma unroll
    for (int k = 0; k < 16; k++) {
      float2 v = cmulf(x[k], weffc);
      float rx = __shfl_xor(v.x, 16);
      float ry = __shfl_xor(v.y, 16);
      x[k] = make_float2(fmaf(v.x, s, rx), fmaf(v.y, s, ry));
    }
    r16_inv(x, wA2t);
    #pragma unroll
    for (int k = 0; k < 16; k++) z[Gb + 32*k + (j5 ^ k)] = x[k];
  }
  __syncthreads();
  // ---- P5: r16 inv (t=512), regs->global (+ D*u) ----
  {
    int xc = (tid >> 5) & 15; int p0 = tid ^ xc;
    #pragma unroll
    for (int k = 0; k < 16; k++) x[k] = z[p0 + 512*k];
    r16_inv(x, wA1);
    const float Dv = Dp[0];
    float* o0 = out + (size_t)r0*LSEQ;
    float* o1 = out + (size_t)r1*LSEQ;
    #pragma unroll
    for (int k = 0; k < 8; k++) {
      int idx = tid + 512*k;
      o0[idx] = x[k].x + Dv*u0[idx];
      o1[idx] = x[k].y + Dv*u1[idx];
    }
  }
}

extern "C" void kernel_launch(void* const* d_in, const int* in_sizes, int n_in,
                              void* d_out, int out_size, void* d_ws, size_t ws_size,
                              hipStream_t stream) {
  const float* u     = (const float*)d_in[0];
  const float* Lre   = (const float*)d_in[1];
  const float* Lim   = (const float*)d_in[2];
  const float* Pre   = (const float*)d_in[3];
  const float* Pim   = (const float*)d_in[4];
  const float* Bre   = (const float*)d_in[5];
  const float* Bim   = (const float*)d_in[6];
  const float* Cri   = (const float*)d_in[7];
  const float* Dp    = (const float*)d_in[8];
  const float* lstep = (const float*)d_in[9];
  float* out = (float*)d_out;

  char* ws = (char*)d_ws;
  float2* a_ws  = (float2*)(ws);            //  32768 B : at_roots
  float*  K_ws  = (float*)(ws + 32768);     //  16384 B : K time domain
  float2* Kd_ws = (float2*)(ws + 49152);    //  65536 B : Kd (logical order, /M)
  float2* ct_ws = (float2*)(ws + 114688);   //   4480 B : twiddle tables (560 entries)

  hipLaunchKernelGGL(tables_kernel, dim3(3),    dim3(256), 0, stream, ct_ws);
  hipLaunchKernelGGL(cauchy_kernel, dim3(64),   dim3(64),  0, stream,
                     Lre, Lim, Pre, Pim, Bre, Bim, Cri, lstep, a_ws);
  hipLaunchKernelGGL(ktime_kernel,  dim3(1024), dim3(256), 0, stream, a_ws, K_ws);
  hipLaunchKernelGGL(kd_kernel,     dim3(1),    dim3(TMAIN), 0, stream,
                     K_ws, ct_ws, Kd_ws);
  hipLaunchKernelGGL(conv_kernel,   dim3(NBH/2), dim3(TMAIN), 0, stream,
                     u, Dp, ct_ws, Kd_ws, out);
}

// Round 4
// 126.159 us; speedup vs baseline: 2.1222x; 2.1222x over previous
//
#include <hip/hip_runtime.h>
#include <math.h>

#define LSEQ 4096
#define MFFT 8192
#define NM   64
#define NBH  4096
#define TMAIN 512

__device__ __forceinline__ float2 cmulf(float2 a, float2 b) {
  return make_float2(a.x*b.x - a.y*b.y, a.x*b.y + a.y*b.x);
}
__device__ __forceinline__ float2 caddf(float2 a, float2 b){ return make_float2(a.x+b.x, a.y+b.y); }
__device__ __forceinline__ float2 csubf(float2 a, float2 b){ return make_float2(a.x-b.x, a.y-b.y); }
__device__ __forceinline__ float2 conjf(float2 a){ return make_float2(a.x, -a.y); }

// ---- radix-4 butterflies (identical math to the validated r1 kernel) ----
__device__ __forceinline__ void r4_fwd(float2& x0, float2& x1, float2& x2, float2& x3,
                                       float2 w1, float2 w2, float2 w3) {
  float2 A = caddf(x0,x2), C = csubf(x0,x2);
  float2 B = caddf(x1,x3), D = csubf(x1,x3);
  float2 y1 = make_float2(C.x + D.y, C.y - D.x);   // C - iD
  float2 y3 = make_float2(C.x - D.y, C.y + D.x);   // C + iD
  x0 = caddf(A,B);
  x1 = cmulf(y1,w1);
  x2 = cmulf(csubf(A,B),w2);
  x3 = cmulf(y3,w3);
}
__device__ __forceinline__ void r4_inv(float2& y0, float2& y1, float2& y2, float2& y3,
                                       float2 w1c, float2 w2c, float2 w3c) {
  float2 c1 = cmulf(y1,w1c);
  float2 c2 = cmulf(y2,w2c);
  float2 c3 = cmulf(y3,w3c);
  float2 ap = caddf(y0,c2), bp = csubf(y0,c2);
  float2 cp = caddf(c1,c3);
  float2 dp = make_float2(c3.y - c1.y, c1.x - c3.x);  // i*(c1-c3)
  y0 = caddf(ap,cp); y1 = caddf(bp,dp); y2 = csubf(ap,cp); y3 = csubf(bp,dp);
}

// compile-time twiddle constants: c16[k]=W16^k, c8[k]=W16^2k, c163[k]=W16^3k (W=e^-2pi i/16)
#define DECL_CONSTS \
  const float C16R[4]={1.f,0.9238795325112867f,0.7071067811865476f,0.3826834323650898f}; \
  const float C16I[4]={0.f,-0.3826834323650898f,-0.7071067811865476f,-0.9238795325112867f}; \
  const float C8R[4] ={1.f,0.7071067811865476f,0.f,-0.7071067811865476f}; \
  const float C8I[4] ={0.f,-0.7071067811865476f,-1.f,-0.7071067811865476f}; \
  const float C163R[4]={1.f,0.3826834323650898f,-0.7071067811865476f,-0.9238795325112867f}; \
  const float C163I[4]={0.f,-0.9238795325112867f,-0.7071067811865476f,0.3826834323650898f};

// fused radix-16 forward = radix-4 at stride 4t then radix-4 at stride t (in regs)
__device__ __forceinline__ void r16_fwd(float2 x[16], float2 wA) {
  DECL_CONSTS
  float2 wA2 = cmulf(wA,wA), wA3 = cmulf(wA2,wA);
  #pragma unroll
  for (int k0 = 0; k0 < 4; k0++) {
    float2 w1 = cmulf(wA,  make_float2(C16R[k0],C16I[k0]));
    float2 w2 = cmulf(wA2, make_float2(C8R[k0], C8I[k0]));
    float2 w3 = cmulf(wA3, make_float2(C163R[k0],C163I[k0]));
    r4_fwd(x[k0], x[k0+4], x[k0+8], x[k0+12], w1, w2, w3);
  }
  float2 wB = cmulf(wA2,wA2);
  float2 wB2 = cmulf(wB,wB), wB3 = cmulf(wB2,wB);
  #pragma unroll
  for (int q = 0; q < 4; q++)
    r4_fwd(x[4*q], x[4*q+1], x[4*q+2], x[4*q+3], wB, wB2, wB3);
}
// fused radix-16 inverse: levels reversed, twiddles conjugated
__device__ __forceinline__ void r16_inv(float2 x[16], float2 wA) {
  DECL_CONSTS
  float2 wA2 = cmulf(wA,wA), wA3 = cmulf(wA2,wA);
  float2 wB = cmulf(wA2,wA2);
  float2 wB2 = cmulf(wB,wB), wB3 = cmulf(wB2,wB);
  float2 wBc = conjf(wB), wB2c = conjf(wB2), wB3c = conjf(wB3);
  #pragma unroll
  for (int q = 0; q < 4; q++)
    r4_inv(x[4*q], x[4*q+1], x[4*q+2], x[4*q+3], wBc, wB2c, wB3c);
  #pragma unroll
  for (int k0 = 0; k0 < 4; k0++) {
    float2 w1c = conjf(cmulf(wA,  make_float2(C16R[k0],C16I[k0])));
    float2 w2c = conjf(cmulf(wA2, make_float2(C8R[k0], C8I[k0])));
    float2 w3c = conjf(cmulf(wA3, make_float2(C163R[k0],C163I[k0])));
    r4_inv(x[k0], x[k0+4], x[k0+8], x[k0+12], w1c, w2c, w3c);
  }
}

// ---------------- prep: twiddle tables ----------------
// ctg[0..511]   = W^t        (P1/P5, t = tid)
// ctg[512..543] = W^{16 j}   (P2/P4, j = tid&31)
// ctg[544..559] = W^{256 c}  (r2 stage, c = tid&15)       W = e^{-2pi i/8192}
__global__ void tables_kernel(float2* __restrict__ ctg) {
  int t = blockIdx.x*blockDim.x + threadIdx.x;
  if (t >= 560) return;
  int e = (t < 512) ? t : (t < 544) ? 16*(t-512) : 256*(t-544);
  double ang = -2.0*M_PI*(double)e/(double)MFFT;
  ctg[t] = make_float2((float)cos(ang), (float)sin(ang));
}

// ---------------- prep: at_roots[k] via 4 Cauchy dots (double precision) ----------------
__global__ void cauchy_kernel(const float* __restrict__ Lre, const float* __restrict__ Lim,
                              const float* __restrict__ Pre, const float* __restrict__ Pim,
                              const float* __restrict__ Bre, const float* __restrict__ Bim,
                              const float* __restrict__ Cri, const float* __restrict__ lstep,
                              float2* __restrict__ a_out) {
  int k = blockIdx.x*blockDim.x + threadIdx.x;
  if (k >= LSEQ) return;
  double step = exp((double)lstep[0]);
  double ang = -2.0*M_PI*(double)k/(double)LSEQ;
  double wr = cos(ang), wi = sin(ang);
  double nr = 1.0 - wr, ni = -wi;
  double dr = 1.0 + wr, di = wi;
  double dn = dr*dr + di*di;
  double gre = (2.0/step) * (nr*dr + ni*di)/dn;
  double gim = (2.0/step) * (ni*dr - nr*di)/dn;
  double cre = 2.0*dr/dn, cim = -2.0*di/dn;
  double k00r=0,k00i=0,k01r=0,k01i=0,k10r=0,k10i=0,k11r=0,k11i=0;
  for (int n = 0; n < NM; n++) {
    double lre = Lre[n], lim = Lim[n];
    double pre = Pre[n], pim = Pim[n];
    double bre = Bre[n], bim = Bim[n];
    double ccr = Cri[2*n], cci = Cri[2*n+1];
    double er = gre - lre, ei = gim - lim;
    double inv = 1.0/(er*er + ei*ei);
    double ir =  er*inv, ii = -ei*inv;
    double v00r = ccr*bre + cci*bim, v00i = ccr*bim - cci*bre;
    double v01r = ccr*pre + cci*pim, v01i = ccr*pim - cci*pre;
    double v10r = pre*bre + pim*bim, v10i = pre*bim - pim*bre;
    double v11r = pre*pre + pim*pim, v11i = 0.0;
    k00r += v00r*ir - v00i*ii;  k00i += v00r*ii + v00i*ir;
    k01r += v01r*ir - v01i*ii;  k01i += v01r*ii + v01i*ir;
    k10r += v10r*ir - v10i*ii;  k10i += v10r*ii + v10i*ir;
    k11r += v11r*ir - v11i*ii;  k11i += v11r*ii + v11i*ir;
  }
  double numr = k01r*k10r - k01i*k10i, numi = k01r*k10i + k01i*k10r;
  double der = 1.0 + k11r, dei = k11i;
  double dinv = 1.0/(der*der + dei*dei);
  double qr = (numr*der + numi*dei)*dinv;
  double qi = (numi*der - numr*dei)*dinv;
  double tr = k00r - qr, ti = k00i - qi;
  double ar = cre*tr - cim*ti, ai = cre*ti + cim*tr;
  a_out[k] = make_float2((float)ar, (float)ai);
}

// ---------------- prep: K[l] = Re(IDFT_L(a))[l], 64 lanes per output ----------------
__global__ void ktime_kernel(const float2* __restrict__ a, float* __restrict__ K) {
  int lane = threadIdx.x & 63;
  int l = blockIdx.x * (blockDim.x >> 6) + (threadIdx.x >> 6);
  if (l >= LSEQ) return;
  double ang0 = 2.0*M_PI*(double)((l*lane) & (LSEQ-1))/(double)LSEQ;
  double tr = cos(ang0), ti = sin(ang0);
  double ang1 = 2.0*M_PI*(double)(l & 63)/64.0;
  double wr = cos(ang1), wi = sin(ang1);
  double acc = 0.0;
  for (int k = 0; k < 64; k++) {
    float2 ak = a[lane + (k << 6)];
    acc += (double)ak.x*tr - (double)ak.y*ti;
    double ntr = tr*wr - ti*wi;
    ti = tr*wi + ti*wr;
    tr = ntr;
  }
  for (int off = 32; off > 0; off >>= 1) acc += __shfl_down(acc, off);
  if (lane == 0) K[l] = (float)(acc/(double)LSEQ);
}

// ---------------- prep: Kd = fwd chain(pad(K)) / M, stored at logical slot 16*tid+c ----
__global__ void kd_kernel(const float* __restrict__ K, const float2* __restrict__ ctg,
                          float2* __restrict__ Kd) {
  __shared__ float2 z[MFFT];
  const int tid = threadIdx.x;
  float2 x[16];
  // P1: t=512
  #pragma unroll
  for (int k = 0; k < 8; k++) x[k] = make_float2(K[tid + 512*k], 0.f);
  #pragma unroll
  for (int k = 8; k < 16; k++) x[k] = make_float2(0.f, 0.f);
  r16_fwd(x, ctg[tid]);
  {
    int xc = (tid >> 5) & 15; int p0 = tid ^ xc;
    #pragma unroll
    for (int k = 0; k < 16; k++) z[p0 + 512*k] = x[k];
  }
  __syncthreads();
  // P2: t=32 + r2(s=16) tail via shfl
  const int j5 = tid & 31;
  const int Gb = (tid >> 5) << 9;
  #pragma unroll
  for (int k = 0; k < 16; k++) x[k] = z[Gb + 32*k + (j5 ^ k)];
  r16_fwd(x, ctg[512 + j5]);
  {
    bool hi = (tid >> 4) & 1;
    float2 w32 = ctg[544 + (tid & 15)];
    float2 weff = hi ? w32 : make_float2(1.f, 0.f);
    float s = hi ? -1.f : 1.f;
    #pragma unroll
    for (int k = 0; k < 16; k++) {
      float rx = __shfl_xor(x[k].x, 16);
      float ry = __shfl_xor(x[k].y, 16);
      float2 pre = make_float2(fmaf(x[k].x, s, rx), fmaf(x[k].y, s, ry));
      x[k] = cmulf(pre, weff);
    }
  }
  #pragma unroll
  for (int k = 0; k < 16; k++) z[Gb + 32*k + (j5 ^ k)] = x[k];
  __syncthreads();
  // P3: consecutive, constant-twiddle r16, scale, store
  {
    int xc = (tid >> 1) & 15; int b16 = tid << 4;
    #pragma unroll
    for (int c = 0; c < 16; c++) x[c] = z[b16 + (c ^ xc)];
    r16_fwd(x, make_float2(1.f, 0.f));
    const float sc = 1.0f/(float)MFFT;
    #pragma unroll
    for (int c = 0; c < 16; c++)
      Kd[b16 + c] = make_float2(x[c].x*sc, x[c].y*sc);
  }
}

// ---------------- main: 2 rows per block, 5 passes, 4 barriers ----------------
// __launch_bounds__(512, 2): cap at 2 resident blocks/CU -> VGPR budget 128/thread.
// (512, 4) forced a 64-VGPR cap and spilled x[16]+kd[8] to scratch: +840 MB HBM, 2x slower.
__global__ __launch_bounds__(TMAIN, 2)
void conv_kernel(const float* __restrict__ u, const float* __restrict__ Dp,
                 const float2* __restrict__ ctg, const float2* __restrict__ Kd,
                 float* __restrict__ out) {
  __shared__ float2 z[MFFT];
  const int tid = threadIdx.x;
  const int r0 = blockIdx.x, r1 = blockIdx.x + (NBH/2);
  const float* u0 = u + (size_t)r0*LSEQ;
  const float* u1 = u + (size_t)r1*LSEQ;
  float2 x[16];
  // ---- P1: global->regs, r16 fwd (t=512), regs->LDS ----
  #pragma unroll
  for (int k = 0; k < 8; k++)
    x[k] = make_float2(u0[tid + 512*k], u1[tid + 512*k]);
  #pragma unroll
  for (int k = 8; k < 16; k++) x[k] = make_float2(0.f, 0.f);
  const float2 wA1 = ctg[tid];
  r16_fwd(x, wA1);
  {
    int xc = (tid >> 5) & 15; int p0 = tid ^ xc;
    #pragma unroll
    for (int k = 0; k < 16; k++) z[p0 + 512*k] = x[k];
  }
  __syncthreads();
  // ---- P2: r16 fwd (t=32) + r2(s=16) tail via shfl_xor(16) ----
  const int j5 = tid & 31;
  const int Gb = (tid >> 5) << 9;
  #pragma unroll
  for (int k = 0; k < 16; k++) x[k] = z[Gb + 32*k + (j5 ^ k)];
  const float2 wA2t = ctg[512 + j5];
  r16_fwd(x, wA2t);
  {
    bool hi = (tid >> 4) & 1;
    float2 w32 = ctg[544 + (tid & 15)];
    float2 weff = hi ? w32 : make_float2(1.f, 0.f);
    float s = hi ? -1.f : 1.f;
    #pragma unroll
    for (int k = 0; k < 16; k++) {
      float rx = __shfl_xor(x[k].x, 16);
      float ry = __shfl_xor(x[k].y, 16);
      float2 pre = make_float2(fmaf(x[k].x, s, rx), fmaf(x[k].y, s, ry));
      x[k] = cmulf(pre, weff);
    }
  }
  #pragma unroll
  for (int k = 0; k < 16; k++) z[Gb + 32*k + (j5 ^ k)] = x[k];
  __syncthreads();
  // ---- P3: consecutive; const-twiddle r16 fwd; x Kd; const-twiddle r16 inv ----
  {
    int xc = (tid >> 1) & 15; int b16 = tid << 4;
    #pragma unroll
    for (int c = 0; c < 16; c++) x[c] = z[b16 + (c ^ xc)];
    float4 kd[8];
    const float4* Kd4 = (const float4*)(Kd + b16);
    #pragma unroll
    for (int q = 0; q < 8; q++) kd[q] = Kd4[q];
    r16_fwd(x, make_float2(1.f, 0.f));
    #pragma unroll
    for (int c = 0; c < 8; c++) {
      x[2*c]   = cmulf(x[2*c],   make_float2(kd[c].x, kd[c].y));
      x[2*c+1] = cmulf(x[2*c+1], make_float2(kd[c].z, kd[c].w));
    }
    r16_inv(x, make_float2(1.f, 0.f));
    #pragma unroll
    for (int c = 0; c < 16; c++) z[b16 + (c ^ xc)] = x[c];
  }
  __syncthreads();
  // ---- P4: inv r2(s=16) head via shfl + r16 inv (t=32) ----
  {
    #pragma unroll
    for (int k = 0; k < 16; k++) x[k] = z[Gb + 32*k + (j5 ^ k)];
    bool hi = (tid >> 4) & 1;
    float2 w32 = ctg[544 + (tid & 15)];
    float2 weffc = hi ? conjf(w32) : make_float2(1.f, 0.f);
    float s = hi ? -1.f : 1.f;
    #pragma unroll
    for (int k = 0; k < 16; k++) {
      float2 v = cmulf(x[k], weffc);
      float rx = __shfl_xor(v.x, 16);
      float ry = __shfl_xor(v.y, 16);
      x[k] = make_float2(fmaf(v.x, s, rx), fmaf(v.y, s, ry));
    }
    r16_inv(x, wA2t);
    #pragma unroll
    for (int k = 0; k < 16; k++) z[Gb + 32*k + (j5 ^ k)] = x[k];
  }
  __syncthreads();
  // ---- P5: r16 inv (t=512), regs->global (+ D*u) ----
  {
    int xc = (tid >> 5) & 15; int p0 = tid ^ xc;
    #pragma unroll
    for (int k = 0; k < 16; k++) x[k] = z[p0 + 512*k];
    r16_inv(x, wA1);
    const float Dv = Dp[0];
    float* o0 = out + (size_t)r0*LSEQ;
    float* o1 = out + (size_t)r1*LSEQ;
    #pragma unroll
    for (int k = 0; k < 8; k++) {
      int idx = tid + 512*k;
      o0[idx] = x[k].x + Dv*u0[idx];
      o1[idx] = x[k].y + Dv*u1[idx];
    }
  }
}

extern "C" void kernel_launch(void* const* d_in, const int* in_sizes, int n_in,
                              void* d_out, int out_size, void* d_ws, size_t ws_size,
                              hipStream_t stream) {
  const float* u     = (const float*)d_in[0];
  const float* Lre   = (const float*)d_in[1];
  const float* Lim   = (const float*)d_in[2];
  const float* Pre   = (const float*)d_in[3];
  const float* Pim   = (const float*)d_in[4];
  const float* Bre   = (const float*)d_in[5];
  const float* Bim   = (const float*)d_in[6];
  const float* Cri   = (const float*)d_in[7];
  const float* Dp    = (const float*)d_in[8];
  const float* lstep = (const float*)d_in[9];
  float* out = (float*)d_out;

  char* ws = (char*)d_ws;
  float2* a_ws  = (float2*)(ws);            //  32768 B : at_roots
  float*  K_ws  = (float*)(ws + 32768);     //  16384 B : K time domain
  float2* Kd_ws = (float2*)(ws + 49152);    //  65536 B : Kd (logical order, /M)
  float2* ct_ws = (float2*)(ws + 114688);   //   4480 B : twiddle tables (560 entries)

  hipLaunchKernelGGL(tables_kernel, dim3(3),    dim3(256), 0, stream, ct_ws);
  hipLaunchKernelGGL(cauchy_kernel, dim3(64),   dim3(64),  0, stream,
                     Lre, Lim, Pre, Pim, Bre, Bim, Cri, lstep, a_ws);
  hipLaunchKernelGGL(ktime_kernel,  dim3(1024), dim3(256), 0, stream, a_ws, K_ws);
  hipLaunchKernelGGL(kd_kernel,     dim3(1),    dim3(TMAIN), 0, stream,
                     K_ws, ct_ws, Kd_ws);
  hipLaunchKernelGGL(conv_kernel,   dim3(NBH/2), dim3(TMAIN), 0, stream,
                     u, Dp, ct_ws, Kd_ws, out);
}